// Round 1
// baseline (356.178 us; speedup 1.0000x reference)
//
#include <hip/hip_runtime.h>

// Problem constants
//  N=8, C=512, P=64, G=8, S_D=512, H=W=128, HW=16384
//  style: [8,512,32,32]  predicted: [8,512,128,128]
//  W1:[512,512] b1:[512] W2:[32768,512] b2:[32768] Wb1:[512,512] bb1:[512] Wb2:[512,512] bb2:[512]

__device__ __forceinline__ float lrelu(float v) { return v > 0.f ? v : 0.01f * v; }

// ---------- K1: adaptive avg pool of style -> s[8*512] ----------
__global__ void k_pool(const float* __restrict__ style, float* __restrict__ s) {
    __shared__ float red[256];
    int b = blockIdx.x;                       // n*512 + c
    const float4* p4 = (const float4*)(style + (size_t)b * 1024);
    float4 x = p4[threadIdx.x];               // 1024/4 = 256 float4
    float v = x.x + x.y + x.z + x.w;
    red[threadIdx.x] = v;
    __syncthreads();
    for (int off = 128; off > 0; off >>= 1) {
        if (threadIdx.x < off) red[threadIdx.x] += red[threadIdx.x + off];
        __syncthreads();
    }
    if (threadIdx.x == 0) s[b] = red[0] * (1.f / 1024.f);
}

// ---------- K2: hk = lrelu(s@W1^T+b1), hb = lrelu(s@Wb1^T+bb1) ----------
// grid 8 (one block per n), block 512 (one thread per out channel)
__global__ void k_mlp1(const float* __restrict__ s, const float* __restrict__ W1,
                       const float* __restrict__ b1, const float* __restrict__ Wb1,
                       const float* __restrict__ bb1, float* __restrict__ hk,
                       float* __restrict__ hb) {
    __shared__ float sv[512];
    int n = blockIdx.x, c = threadIdx.x;
    sv[c] = s[n * 512 + c];
    __syncthreads();
    float a = 0.f, bacc = 0.f;
    const float* w1 = W1 + (size_t)c * 512;
    const float* wb = Wb1 + (size_t)c * 512;
    for (int k = 0; k < 512; ++k) { a += sv[k] * w1[k]; bacc += sv[k] * wb[k]; }
    a += b1[c]; bacc += bb1[c];
    hk[n * 512 + c] = lrelu(a);
    hb[n * 512 + c] = lrelu(bacc);
}

// ---------- K3: kn[n,32768] = hk@W2^T+b2 ; bvec[n,512] = hb@Wb2^T+bb2 ----------
// one wave per output row, 4 waves/block; rows 0..32767 -> kn, 32768..33279 -> bvec
__global__ void k_mlp2(const float* __restrict__ hk, const float* __restrict__ hb,
                       const float* __restrict__ W2, const float* __restrict__ b2,
                       const float* __restrict__ Wb2, const float* __restrict__ bb2,
                       float* __restrict__ kn, float* __restrict__ bvec) {
    __shared__ float h[8192];                 // hk[8*512] then hb[8*512]
    for (int i = threadIdx.x; i < 4096; i += 256) { h[i] = hk[i]; h[4096 + i] = hb[i]; }
    __syncthreads();
    int wave = threadIdx.x >> 6, lane = threadIdx.x & 63;
    int row = blockIdx.x * 4 + wave;          // 0..33279
    const float* wrow;
    const float* hbase;
    float bias;
    int r2 = row - 32768;
    if (row < 32768) { wrow = W2 + (size_t)row * 512; hbase = h; bias = b2[row]; }
    else             { wrow = Wb2 + (size_t)r2 * 512; hbase = h + 4096; bias = bb2[r2]; }
    float acc[8] = {0.f,0.f,0.f,0.f,0.f,0.f,0.f,0.f};
    for (int k = lane; k < 512; k += 64) {
        float w = wrow[k];
        #pragma unroll
        for (int n = 0; n < 8; ++n) acc[n] += w * hbase[n * 512 + k];
    }
    #pragma unroll
    for (int n = 0; n < 8; ++n) {
        float v = acc[n];
        for (int off = 32; off > 0; off >>= 1) v += __shfl_xor(v, off, 64);
        acc[n] = v;
    }
    if (lane == 0) {
        if (row < 32768) {
            #pragma unroll
            for (int n = 0; n < 8; ++n) kn[(size_t)n * 32768 + row] = acc[n] + bias;
        } else {
            #pragma unroll
            for (int n = 0; n < 8; ++n) bvec[n * 512 + r2] = acc[n] + bias;
        }
    }
}

// ---------- K4: per-(n,c) mean & rsqrt(var+eps) over 16384 pixels ----------
__global__ void k_stats(const float* __restrict__ x, float* __restrict__ mu,
                        float* __restrict__ rs) {
    __shared__ float rsum[256], rsq[256];
    int b = blockIdx.x;                       // n*512 + c
    int tid = threadIdx.x;
    const float4* p4 = (const float4*)(x + (size_t)b * 16384);
    float s = 0.f, q = 0.f;
    #pragma unroll
    for (int i = 0; i < 16; ++i) {
        float4 v = p4[tid + 256 * i];
        s += v.x + v.y + v.z + v.w;
        q += v.x * v.x + v.y * v.y + v.z * v.z + v.w * v.w;
    }
    rsum[tid] = s; rsq[tid] = q;
    __syncthreads();
    for (int off = 128; off > 0; off >>= 1) {
        if (tid < off) { rsum[tid] += rsum[tid + off]; rsq[tid] += rsq[tid + off]; }
        __syncthreads();
    }
    if (tid == 0) {
        float m = rsum[0] * (1.f / 16384.f);
        float v = rsq[0] * (1.f / 16384.f) - m * m;
        mu[b] = m;
        rs[b] = rsqrtf(v + 1e-5f);
    }
}

// ---------- K5: fold norm into kernel:  Kp[o,p]=K[o,p]*rs[p], bp[o]=bias[o]-sum_p Kp[o,p]*mu[p] ----------
// one wave per (n,g,o) row; lane = p
__global__ void k_fold(const float* __restrict__ kn, const float* __restrict__ bvec,
                       const float* __restrict__ mu, const float* __restrict__ rs,
                       float* __restrict__ Kp, float* __restrict__ bp) {
    int wave = threadIdx.x >> 6, lane = threadIdx.x & 63;
    int t = blockIdx.x * 4 + wave;            // 0..4095 = n*512 + g*64 + o
    int n = t >> 9, rem = t & 511, g = rem >> 6, o = rem & 63;
    int ci = n * 512 + g * 64 + lane;         // input-channel index within [n,512)
    float kv = kn[(size_t)n * 32768 + g * 4096 + o * 64 + lane] * rs[ci];
    Kp[(size_t)t * 64 + lane] = kv;
    float pm = kv * mu[ci];
    for (int off = 32; off > 0; off >>= 1) pm += __shfl_xor(pm, off, 64);
    if (lane == 0) bp[t] = bvec[n * 512 + g * 64 + o] - pm;
}

// ---------- K6: main grouped conv sweep  out[o,hw] = sum_p Kp[o,p]*x[p,hw] + bp[o] ----------
// grid: 64 (n,g) * 32 slabs; block 256. Per iteration: 64ch x 128px tile.
__global__ __launch_bounds__(256) void k_conv(const float* __restrict__ x,
                                              const float* __restrict__ Kp,
                                              const float* __restrict__ bp,
                                              float* __restrict__ out) {
    __shared__ float kt[4096];                // 16 KB K' tile
    __shared__ float xs[64 * 128];            // 32 KB x tile
    int bid = blockIdx.x;
    int ng = bid >> 5, slab = bid & 31;
    int n = ng >> 3, g = ng & 7;
    int tid = threadIdx.x;
    // load K' (contiguous 4096 floats at ng*4096)
    const float4* kp4 = (const float4*)(Kp + (size_t)ng * 4096);
    float4* kt4 = (float4*)kt;
    #pragma unroll
    for (int i = 0; i < 4; ++i) kt4[tid + 256 * i] = kp4[tid + 256 * i];
    int ob = tid >> 5, pg = tid & 31;         // ob: 8-output block, pg: 4-pixel group
    float bias[8];
    #pragma unroll
    for (int oi = 0; oi < 8; ++oi) bias[oi] = bp[n * 512 + g * 64 + ob * 8 + oi];
    const float* xbase = x + ((size_t)(n * 512 + g * 64)) * 16384;
    float* obase = out + ((size_t)(n * 512 + g * 64)) * 16384;
    int px0 = slab * 512;
    int r0 = tid >> 5, c4 = (tid & 31) * 4;
    for (int it = 0; it < 4; ++it) {
        int pb = px0 + it * 128;
        __syncthreads();                      // protect xs from previous iter's readers
        #pragma unroll
        for (int rr = 0; rr < 64; rr += 8) {
            float4 v = *(const float4*)(xbase + (size_t)(r0 + rr) * 16384 + pb + c4);
            *(float4*)(xs + (r0 + rr) * 128 + c4) = v;
        }
        __syncthreads();
        float4 acc[8];
        #pragma unroll
        for (int oi = 0; oi < 8; ++oi) acc[oi] = make_float4(bias[oi], bias[oi], bias[oi], bias[oi]);
        #pragma unroll 4
        for (int pc = 0; pc < 64; pc += 4) {
            float4 xv0 = *(const float4*)(xs + (pc + 0) * 128 + pg * 4);
            float4 xv1 = *(const float4*)(xs + (pc + 1) * 128 + pg * 4);
            float4 xv2 = *(const float4*)(xs + (pc + 2) * 128 + pg * 4);
            float4 xv3 = *(const float4*)(xs + (pc + 3) * 128 + pg * 4);
            #pragma unroll
            for (int oi = 0; oi < 8; ++oi) {
                float4 k4 = *(const float4*)(kt + (ob * 8 + oi) * 64 + pc);
                acc[oi].x += k4.x * xv0.x + k4.y * xv1.x + k4.z * xv2.x + k4.w * xv3.x;
                acc[oi].y += k4.x * xv0.y + k4.y * xv1.y + k4.z * xv2.y + k4.w * xv3.y;
                acc[oi].z += k4.x * xv0.z + k4.y * xv1.z + k4.z * xv2.z + k4.w * xv3.z;
                acc[oi].w += k4.x * xv0.w + k4.y * xv1.w + k4.z * xv2.w + k4.w * xv3.w;
            }
        }
        #pragma unroll
        for (int oi = 0; oi < 8; ++oi)
            *(float4*)(obase + (size_t)(ob * 8 + oi) * 16384 + pb + pg * 4) = acc[oi];
    }
}

extern "C" void kernel_launch(void* const* d_in, const int* in_sizes, int n_in,
                              void* d_out, int out_size, void* d_ws, size_t ws_size,
                              hipStream_t stream) {
    const float* style = (const float*)d_in[0];
    const float* pred  = (const float*)d_in[1];
    const float* W1    = (const float*)d_in[2];
    const float* b1    = (const float*)d_in[3];
    const float* W2    = (const float*)d_in[4];
    const float* b2    = (const float*)d_in[5];
    const float* Wb1   = (const float*)d_in[6];
    const float* bb1   = (const float*)d_in[7];
    const float* Wb2   = (const float*)d_in[8];
    const float* bb2   = (const float*)d_in[9];
    float* out = (float*)d_out;

    // workspace layout (floats)
    float* ws   = (float*)d_ws;
    float* s    = ws;                // 4096
    float* hk   = s + 4096;          // 4096
    float* hb   = hk + 4096;         // 4096
    float* kn   = hb + 4096;         // 262144
    float* bvec = kn + 262144;       // 4096
    float* mu   = bvec + 4096;       // 4096
    float* rs   = mu + 4096;         // 4096
    float* Kp   = rs + 4096;         // 262144
    float* bp   = Kp + 262144;       // 4096   (total ~2.2 MB)

    k_pool <<<4096, 256, 0, stream>>>(style, s);
    k_mlp1 <<<8,    512, 0, stream>>>(s, W1, b1, Wb1, bb1, hk, hb);
    k_mlp2 <<<8320, 256, 0, stream>>>(hk, hb, W2, b2, Wb2, bb2, kn, bvec);
    k_stats<<<4096, 256, 0, stream>>>(pred, mu, rs);
    k_fold <<<1024, 256, 0, stream>>>(kn, bvec, mu, rs, Kp, bp);
    k_conv <<<2048, 256, 0, stream>>>(pred, Kp, bp, out);
}

// Round 2
// 218.803 us; speedup vs baseline: 1.6279x; 1.6279x over previous
//
#include <hip/hip_runtime.h>

// Problem constants
//  N=8, C=512, P=64, G=8, S_D=512, H=W=128, HW=16384
//  style: [8,512,32,32]  predicted: [8,512,128,128]

typedef __attribute__((ext_vector_type(8))) short bf16x8;
typedef __attribute__((ext_vector_type(4))) float f32x4;

__device__ __forceinline__ float lrelu(float v) { return v > 0.f ? v : 0.01f * v; }

__device__ __forceinline__ unsigned short f2bf(float f) {
    unsigned int u = __float_as_uint(f);
    unsigned int r = (u + 0x7FFFu + ((u >> 16) & 1u)) >> 16;   // round-nearest-even
    return (unsigned short)r;
}

// ---------- K1: adaptive avg pool of style -> s[8*512]; wave per channel ----------
__global__ void k_pool(const float* __restrict__ style, float* __restrict__ s) {
    int wv = threadIdx.x >> 6, lane = threadIdx.x & 63;
    int b = blockIdx.x * 4 + wv;              // n*512 + c, 0..4095
    const float4* p4 = (const float4*)(style + (size_t)b * 1024);
    float v = 0.f;
    #pragma unroll
    for (int i = 0; i < 4; ++i) {
        float4 t = p4[lane + 64 * i];
        v += t.x + t.y + t.z + t.w;
    }
    #pragma unroll
    for (int off = 32; off > 0; off >>= 1) v += __shfl_xor(v, off, 64);
    if (lane == 0) s[b] = v * (1.f / 1024.f);
}

// ---------- K2: hk = lrelu(s@W1^T+b1), hb = lrelu(s@Wb1^T+bb1) ----------
// wave per output row (rows 0..511 -> W1/hk, 512..1023 -> Wb1/hb), all 8 n per wave
__global__ void k_mlp1(const float* __restrict__ s, const float* __restrict__ W1,
                       const float* __restrict__ b1, const float* __restrict__ Wb1,
                       const float* __restrict__ bb1, float* __restrict__ hk,
                       float* __restrict__ hb) {
    __shared__ float sv[4096];                // s[8][512]
    const float4* s4 = (const float4*)s;
    float4* sv4 = (float4*)sv;
    #pragma unroll
    for (int i = 0; i < 4; ++i) sv4[threadIdx.x + 256 * i] = s4[threadIdx.x + 256 * i];
    __syncthreads();
    int wv = threadIdx.x >> 6, lane = threadIdx.x & 63;
    int row = blockIdx.x * 4 + wv;            // 0..1023
    int r2 = row & 511;
    const float* wrow = (row < 512) ? W1 + (size_t)r2 * 512 : Wb1 + (size_t)r2 * 512;
    float bias = (row < 512) ? b1[r2] : bb1[r2];
    float acc[8] = {0.f,0.f,0.f,0.f,0.f,0.f,0.f,0.f};
    #pragma unroll
    for (int c = 0; c < 2; ++c) {
        float4 w4 = *(const float4*)(wrow + lane * 4 + 256 * c);
        #pragma unroll
        for (int n = 0; n < 8; ++n) {
            float4 h4 = *(const float4*)(sv + n * 512 + lane * 4 + 256 * c);
            acc[n] += w4.x * h4.x + w4.y * h4.y + w4.z * h4.z + w4.w * h4.w;
        }
    }
    #pragma unroll
    for (int n = 0; n < 8; ++n) {
        float v = acc[n];
        #pragma unroll
        for (int off = 32; off > 0; off >>= 1) v += __shfl_xor(v, off, 64);
        acc[n] = v;
    }
    if (lane == 0) {
        float* dst = (row < 512) ? hk : hb;
        #pragma unroll
        for (int n = 0; n < 8; ++n) dst[n * 512 + r2] = lrelu(acc[n] + bias);
    }
}

// ---------- K3: kn[n,32768] = hk@W2^T+b2 ; bvec[n,512] = hb@Wb2^T+bb2 ----------
__global__ void k_mlp2(const float* __restrict__ hk, const float* __restrict__ hb,
                       const float* __restrict__ W2, const float* __restrict__ b2,
                       const float* __restrict__ Wb2, const float* __restrict__ bb2,
                       float* __restrict__ kn, float* __restrict__ bvec) {
    __shared__ float h[8192];                 // hk[8*512] then hb[8*512]
    const float4* hk4 = (const float4*)hk;
    const float4* hb4 = (const float4*)hb;
    float4* h4 = (float4*)h;
    #pragma unroll
    for (int i = 0; i < 4; ++i) {
        h4[threadIdx.x + 256 * i]        = hk4[threadIdx.x + 256 * i];
        h4[1024 + threadIdx.x + 256 * i] = hb4[threadIdx.x + 256 * i];
    }
    __syncthreads();
    int wv = threadIdx.x >> 6, lane = threadIdx.x & 63;
    int row = blockIdx.x * 4 + wv;            // 0..33279
    const float* wrow;
    const float* hbase;
    float bias;
    int r2 = row - 32768;
    if (row < 32768) { wrow = W2 + (size_t)row * 512; hbase = h; bias = b2[row]; }
    else             { wrow = Wb2 + (size_t)r2 * 512; hbase = h + 4096; bias = bb2[r2]; }
    float acc[8] = {0.f,0.f,0.f,0.f,0.f,0.f,0.f,0.f};
    #pragma unroll
    for (int c = 0; c < 2; ++c) {
        float4 w4 = *(const float4*)(wrow + lane * 4 + 256 * c);
        #pragma unroll
        for (int n = 0; n < 8; ++n) {
            float4 x4 = *(const float4*)(hbase + n * 512 + lane * 4 + 256 * c);
            acc[n] += w4.x * x4.x + w4.y * x4.y + w4.z * x4.z + w4.w * x4.w;
        }
    }
    #pragma unroll
    for (int n = 0; n < 8; ++n) {
        float v = acc[n];
        #pragma unroll
        for (int off = 32; off > 0; off >>= 1) v += __shfl_xor(v, off, 64);
        acc[n] = v;
    }
    if (lane == 0) {
        if (row < 32768) {
            #pragma unroll
            for (int n = 0; n < 8; ++n) kn[(size_t)n * 32768 + row] = acc[n] + bias;
        } else {
            #pragma unroll
            for (int n = 0; n < 8; ++n) bvec[n * 512 + r2] = acc[n] + bias;
        }
    }
}

// ---------- K4: per-(n,c) mean & rsqrt(var+eps) over 16384 pixels ----------
__global__ void k_stats(const float* __restrict__ x, float* __restrict__ mu,
                        float* __restrict__ rs) {
    __shared__ float ps[4], pq[4];
    int b = blockIdx.x;                       // n*512 + c
    int tid = threadIdx.x, wv = tid >> 6, lane = tid & 63;
    const float4* p4 = (const float4*)(x + (size_t)b * 16384);
    float s = 0.f, q = 0.f;
    #pragma unroll
    for (int i = 0; i < 16; ++i) {
        float4 v = p4[tid + 256 * i];
        s += v.x + v.y + v.z + v.w;
        q += v.x * v.x + v.y * v.y + v.z * v.z + v.w * v.w;
    }
    #pragma unroll
    for (int off = 32; off > 0; off >>= 1) {
        s += __shfl_xor(s, off, 64);
        q += __shfl_xor(q, off, 64);
    }
    if (lane == 0) { ps[wv] = s; pq[wv] = q; }
    __syncthreads();
    if (tid == 0) {
        float S = ps[0] + ps[1] + ps[2] + ps[3];
        float Q = pq[0] + pq[1] + pq[2] + pq[3];
        float m = S * (1.f / 16384.f);
        float v = Q * (1.f / 16384.f) - m * m;
        mu[b] = m;
        rs[b] = rsqrtf(v + 1e-5f);
    }
}

// ---------- K5: fold norm into kernel; emit bf16 K' + fp32 b' ----------
// wave per (n,g,o) row; lane = p
__global__ void k_fold(const float* __restrict__ kn, const float* __restrict__ bvec,
                       const float* __restrict__ mu, const float* __restrict__ rs,
                       unsigned short* __restrict__ Kp, float* __restrict__ bp) {
    int wv = threadIdx.x >> 6, lane = threadIdx.x & 63;
    int t = blockIdx.x * 4 + wv;              // 0..4095 = n*512 + g*64 + o
    int n = t >> 9, rem = t & 511, g = rem >> 6;
    int ci = n * 512 + g * 64 + lane;
    float kv = kn[(size_t)n * 32768 + (size_t)(rem) * 64 + lane] * rs[ci];
    Kp[(size_t)t * 64 + lane] = f2bf(kv);
    float pm = kv * mu[ci];
    #pragma unroll
    for (int off = 32; off > 0; off >>= 1) pm += __shfl_xor(pm, off, 64);
    if (lane == 0) bp[t] = bvec[n * 512 + rem] - pm;
}

// ---------- K6: MFMA grouped conv: out[o,px] = sum_p K'[o,p]*x[p,px] + b'[o] ----------
// No LDS, no barriers. Wave owns 64 o x 64 px; A (K') entirely in registers.
// grid = 64 ng * 64 slabs, block 256 (4 waves; wave w covers px slab*256 + w*64).
__global__ __launch_bounds__(256) void k_conv(const float* __restrict__ x,
                                              const unsigned short* __restrict__ Kp,
                                              const float* __restrict__ bp,
                                              float* __restrict__ out) {
    int bid = blockIdx.x;
    int ng = bid >> 6, slab = bid & 63;
    int wv = threadIdx.x >> 6, lane = threadIdx.x & 63;
    int l15 = lane & 15, lg = lane >> 4;

    // A fragments: K'[ob*16 + l15][kk*32 + lg*8 + j]
    const unsigned short* kpb = Kp + (size_t)ng * 4096;
    bf16x8 afr[4][2];
    #pragma unroll
    for (int ob = 0; ob < 4; ++ob)
        #pragma unroll
        for (int kk = 0; kk < 2; ++kk)
            afr[ob][kk] = *(const bf16x8*)(kpb + (ob * 16 + l15) * 64 + kk * 32 + lg * 8);

    // bias for D rows: row = lg*4 + r within each 16-o block
    float bias[4][4];
    #pragma unroll
    for (int ob = 0; ob < 4; ++ob)
        #pragma unroll
        for (int r = 0; r < 4; ++r)
            bias[ob][r] = bp[ng * 64 + ob * 16 + lg * 4 + r];

    const size_t xbase = (size_t)ng * 64 * 16384;   // channel p lives at xbase + p*16384
    int px0 = slab * 256 + wv * 64;

    #pragma unroll
    for (int c = 0; c < 4; ++c) {
        int px = px0 + c * 16 + l15;
        // B fragment: x[kk*32 + lg*8 + j][px]
        float xv[2][8];
        #pragma unroll
        for (int kk = 0; kk < 2; ++kk)
            #pragma unroll
            for (int j = 0; j < 8; ++j) {
                int p = kk * 32 + lg * 8 + j;
                xv[kk][j] = x[xbase + (size_t)p * 16384 + px];
            }
        bf16x8 bfr[2];
        #pragma unroll
        for (int kk = 0; kk < 2; ++kk)
            #pragma unroll
            for (int j = 0; j < 8; ++j)
                bfr[kk][j] = (short)f2bf(xv[kk][j]);

        #pragma unroll
        for (int ob = 0; ob < 4; ++ob) {
            f32x4 acc = { bias[ob][0], bias[ob][1], bias[ob][2], bias[ob][3] };
            acc = __builtin_amdgcn_mfma_f32_16x16x32_bf16(afr[ob][0], bfr[0], acc, 0, 0, 0);
            acc = __builtin_amdgcn_mfma_f32_16x16x32_bf16(afr[ob][1], bfr[1], acc, 0, 0, 0);
            #pragma unroll
            for (int r = 0; r < 4; ++r)
                out[(size_t)(ng * 64 + ob * 16 + lg * 4 + r) * 16384 + px] = acc[r];
        }
    }
}

extern "C" void kernel_launch(void* const* d_in, const int* in_sizes, int n_in,
                              void* d_out, int out_size, void* d_ws, size_t ws_size,
                              hipStream_t stream) {
    const float* style = (const float*)d_in[0];
    const float* pred  = (const float*)d_in[1];
    const float* W1    = (const float*)d_in[2];
    const float* b1    = (const float*)d_in[3];
    const float* W2    = (const float*)d_in[4];
    const float* b2    = (const float*)d_in[5];
    const float* Wb1   = (const float*)d_in[6];
    const float* bb1   = (const float*)d_in[7];
    const float* Wb2   = (const float*)d_in[8];
    const float* bb2   = (const float*)d_in[9];
    float* out = (float*)d_out;

    // workspace layout (floats; all offsets 16B-aligned)
    float* ws   = (float*)d_ws;
    float* s    = ws;                 // 4096
    float* hk   = s + 4096;           // 4096
    float* hb   = hk + 4096;          // 4096
    float* kn   = hb + 4096;          // 262144
    float* bvec = kn + 262144;        // 4096
    float* mu   = bvec + 4096;        // 4096
    float* rs   = mu + 4096;          // 4096
    float* bp   = rs + 4096;          // 4096
    unsigned short* Kp = (unsigned short*)(bp + 4096);  // 262144 ushorts

    k_pool <<<1024, 256, 0, stream>>>(style, s);
    k_mlp1 <<<256,  256, 0, stream>>>(s, W1, b1, Wb1, bb1, hk, hb);
    k_mlp2 <<<8320, 256, 0, stream>>>(hk, hb, W2, b2, Wb2, bb2, kn, bvec);
    k_stats<<<4096, 256, 0, stream>>>(pred, mu, rs);
    k_fold <<<1024, 256, 0, stream>>>(kn, bvec, mu, rs, Kp, bp);
    k_conv <<<4096, 256, 0, stream>>>(pred, Kp, bp, out);
}